// Round 1
// baseline (414.553 us; speedup 1.0000x reference)
//
#include <hip/hip_runtime.h>

#define B_ 2
#define N_ 4096
#define M_ 32
#define D_ 128
#define E_ 64
#define LN_EPS 1e-5f
#define WST 136              // bf16 elems/row of w-tile: 272B rows, 16B-aligned
#define TOT (B_ * N_)
#define FGRID 512            // 2 blocks/CU * 256 CU (persistent, exact residency)

typedef __bf16 bf16x8 __attribute__((ext_vector_type(8)));
typedef float  f32x4  __attribute__((ext_vector_type(4)));

// ---------------------------------------------------------------------------
// K1: projections (unchanged). One wave per bn (4 bn / 256-thr block).
// q stored fp32 [bn][e][8]; k stored bf16 [bn][e][8].
// Slots: 0..2 = x1(ml0..2), 3..7 = x2(ml0..4).
// ---------------------------------------------------------------------------
__global__ __launch_bounds__(256) void proj_kernel(
    const float* __restrict__ x1, const float* __restrict__ x2,
    const float* __restrict__ Wq, const float* __restrict__ Wk1,
    const float* __restrict__ Wk2,
    float* __restrict__ qws, __bf16* __restrict__ kws)
{
    __shared__ float xs[4][D_ * 8];
    const int lane = threadIdx.x & 63;
    const int wv   = threadIdx.x >> 6;
    const int bn   = blockIdx.x * 4 + wv;
    float* xw = xs[wv];
    const float* __restrict__ x1p = x1 + (size_t)bn * (D_ * 3);
    const float* __restrict__ x2p = x2 + (size_t)bn * (D_ * 5);
    for (int i = lane; i < D_ * 3; i += 64) xw[(i / 3) * 8 + (i % 3)]     = x1p[i];
    for (int i = lane; i < D_ * 5; i += 64) xw[(i / 5) * 8 + 3 + (i % 5)] = x2p[i];
    __syncthreads();

    float q[8] = {0.f,0.f,0.f,0.f,0.f,0.f,0.f,0.f};
    float k[8] = {0.f,0.f,0.f,0.f,0.f,0.f,0.f,0.f};
    #pragma unroll 4
    for (int d = 0; d < D_; ++d) {
        const float4 xa = *(const float4*)&xw[d * 8];
        const float4 xb = *(const float4*)&xw[d * 8 + 4];
        const float wq  = Wq [d * E_ + lane];
        const float wk1 = Wk1[d * E_ + lane];
        const float wk2 = Wk2[d * E_ + lane];
        q[0] += xa.x * wq;  q[1] += xa.y * wq;  q[2] += xa.z * wq;  q[3] += xa.w * wq;
        q[4] += xb.x * wq;  q[5] += xb.y * wq;  q[6] += xb.z * wq;  q[7] += xb.w * wq;
        k[0] += xa.x * wk1; k[1] += xa.y * wk1; k[2] += xa.z * wk1;
        k[3] += xa.w * wk2; k[4] += xb.x * wk2; k[5] += xb.y * wk2;
        k[6] += xb.z * wk2; k[7] += xb.w * wk2;
    }
    float4* qo = (float4*)(qws + ((size_t)bn * E_ + lane) * 8);
    qo[0] = make_float4(q[0], q[1], q[2], q[3]);
    qo[1] = make_float4(q[4], q[5], q[6], q[7]);
    bf16x8 kb;
    #pragma unroll
    for (int s = 0; s < 8; ++s) kb[s] = (__bf16)k[s];
    *(bf16x8*)(kws + ((size_t)bn * E_ + lane) * 8) = kb;
}

// ---------------------------------------------------------------------------
// K2: fused gather + LN + dual MFMA matmul + epilogue. RESTRUCTURED:
//   * 512-thr blocks, 8 waves, each wave owns a 16-col output slice.
//     Halves B-frags (32 VGPR), acc (16), kv (16) vs the 4-wave version,
//     buying room to prefetch EVERYTHING one iteration ahead.
//   * Per-iteration pipeline (triple-buffered w-tile, ONE barrier):
//       phaseW(bn+s)   <- consumes kv/q prefetched LAST iteration (no stall)
//       __syncthreads  <- drains nothing (all in-flight loads already used)
//       phaseM(bn)     <- tf (both t halves) prefetched LAST iteration
//       gatherIssue(bn+2s)  <- POST-barrier: consumed pre-barrier next iter,
//                              so syncthreads' vmcnt(0) drain never hits it
//       nidxLoad(bn+3s)     <- 2 iters ahead of its gather
//       tload(bn+s)         <- t loads + cvt; its tail stall also covers the
//                              just-issued gather latency
//   * Triple buffer + single barrier race-free as before: write of buffer X
//     (iter i, pre-barrier) vs prior read of X (iter i-2, post-barrier) is
//     separated by barrier i-1.
// ---------------------------------------------------------------------------
__global__ __launch_bounds__(512, 4) void fused_kernel(
    const float* __restrict__ t_ij, const int* __restrict__ nidx,
    const float* __restrict__ qws, const __bf16* __restrict__ kws,
    const float* __restrict__ ln_w,
    const float* __restrict__ edge_w, const float* __restrict__ res_w,
    float* __restrict__ out)
{
    __shared__ __bf16 wbuf[3][M_ * WST];

    const int t    = threadIdx.x;
    const int lane = t & 63;
    const int wvu  = t >> 6;            // 0..7
    const int r16  = lane & 15;
    const int quad = lane >> 4;
    const int n0   = wvu * 16;          // this wave's 16-col output slice

    // ---- persistent B-fragments (fp32 global -> bf16 regs), one-time ----
    // B[k][n]: lane holds k = ks*32 + quad*8 + j, n = n0 + r16.
    bf16x8 bE[4], bR[4];
    #pragma unroll
    for (int ks = 0; ks < 4; ++ks) {
        const int k0 = ks * 32 + quad * 8;
        bf16x8 fe, fr;
        #pragma unroll
        for (int j = 0; j < 8; ++j) {
            fe[j] = (__bf16)edge_w[(k0 + j) * D_ + n0 + r16];
            fr[j] = (__bf16)res_w [(k0 + j) * D_ + n0 + r16];
        }
        bE[ks] = fe;
        bR[ks] = fr;
    }

    const float lnlo = ln_w[lane];
    const float lnhi = ln_w[64 + lane];
    const int stride = gridDim.x;

    // ---- pipeline registers ----
    int    ni[4];        // neighbor idx for the NEXT gather's bn
    bf16x8 kv[4];        // gathered k rows for the NEXT phaseW's bn
    float4 qa, qb;       // q for the NEXT phaseW's bn
    bf16x8 tf[8];        // t_ij A-frags (BOTH mt halves) for next phaseM's bn

    auto nidxLoad = [&](int bn) {
        const int* np = nidx + (size_t)bn * M_ + wvu * 4;
        #pragma unroll
        for (int jj = 0; jj < 4; ++jj) ni[jj] = np[jj];
    };
    auto gatherIssue = [&](int bn) {
        const int b = bn >> 12;
        #pragma unroll
        for (int jj = 0; jj < 4; ++jj)
            kv[jj] = *(const bf16x8*)&kws[((size_t)(b * N_ + ni[jj]) * E_ + lane) * 8];
        const float* qp = qws + ((size_t)bn * E_ + lane) * 8;
        qa = *(const float4*)qp;
        qb = *(const float4*)(qp + 4);
    };

    // ---- phase W: compute+LN 4 j-rows of w into an LDS buffer ----
    auto phaseW = [&](__bf16* buf) {
        #pragma unroll
        for (int jj = 0; jj < 4; ++jj) {
            const int j = wvu * 4 + jj;
            const bf16x8 k8 = kv[jj];
            const float wlo = qa.x * (float)k8[0] + qa.y * (float)k8[1]
                            + qa.z * (float)k8[2];
            const float whi = qa.w * (float)k8[3] + qb.x * (float)k8[4]
                            + qb.y * (float)k8[5] + qb.z * (float)k8[6]
                            + qb.w * (float)k8[7];
            float s1 = wlo + whi;
            float s2 = wlo * wlo + whi * whi;
            #pragma unroll
            for (int off = 1; off < 64; off <<= 1) {
                s1 += __shfl_xor(s1, off, 64);
                s2 += __shfl_xor(s2, off, 64);
            }
            const float mu  = s1 * (1.f / 128.f);
            const float var = fmaxf(s2 * (1.f / 128.f) - mu * mu, 0.f);
            const float rs  = rsqrtf(var + LN_EPS);
            buf[j * WST + lane]      = (__bf16)((wlo - mu) * rs * lnlo);
            buf[j * WST + 64 + lane] = (__bf16)((whi - mu) * rs * lnhi);
        }
    };

    // ---- t_ij prefetch, BOTH mt halves, packed to bf16 A-frags ----
    auto tload = [&](int bn) {
        const float* tp = t_ij + ((size_t)bn * M_) * D_;
        #pragma unroll
        for (int mt = 0; mt < 2; ++mt) {
            const float* tpr = tp + (size_t)(mt * 16 + r16) * D_;
            #pragma unroll
            for (int ks = 0; ks < 4; ++ks) {
                const int ko = ks * 32 + quad * 8;
                const float4 t0 = *(const float4*)(tpr + ko);
                const float4 t1 = *(const float4*)(tpr + ko + 4);
                bf16x8 a;
                a[0]=(__bf16)t0.x; a[1]=(__bf16)t0.y; a[2]=(__bf16)t0.z; a[3]=(__bf16)t0.w;
                a[4]=(__bf16)t1.x; a[5]=(__bf16)t1.y; a[6]=(__bf16)t1.z; a[7]=(__bf16)t1.w;
                tf[mt * 4 + ks] = a;
            }
        }
    };

    // ---- phase M: dual matmul for this wave's 16 cols + fused epilogue ----
    auto phaseM = [&](int bn, const __bf16* buf) {
        const size_t jb = (size_t)bn * M_;
        f32x4 accE[2], accR[2];
        #pragma unroll
        for (int mt = 0; mt < 2; ++mt) {
            accE[mt] = (f32x4){0.f,0.f,0.f,0.f};
            accR[mt] = (f32x4){0.f,0.f,0.f,0.f};
        }
        #pragma unroll
        for (int ks = 0; ks < 4; ++ks) {
            const bf16x8 aW0 = *(const bf16x8*)&buf[r16 * WST + ks * 32 + quad * 8];
            const bf16x8 aW1 = *(const bf16x8*)&buf[(16 + r16) * WST + ks * 32 + quad * 8];
            accE[0] = __builtin_amdgcn_mfma_f32_16x16x32_bf16(aW0,      bE[ks], accE[0], 0, 0, 0);
            accR[0] = __builtin_amdgcn_mfma_f32_16x16x32_bf16(tf[ks],   bR[ks], accR[0], 0, 0, 0);
            accE[1] = __builtin_amdgcn_mfma_f32_16x16x32_bf16(aW1,      bE[ks], accE[1], 0, 0, 0);
            accR[1] = __builtin_amdgcn_mfma_f32_16x16x32_bf16(tf[4+ks], bR[ks], accR[1], 0, 0, 0);
        }
        #pragma unroll
        for (int mt = 0; mt < 2; ++mt)
            #pragma unroll
            for (int rr = 0; rr < 4; ++rr) {
                const int row = mt * 16 + quad * 4 + rr;
                const float e  = accE[mt][rr];
                const float sg = 1.f / (1.f + __expf(-e));
                out[(jb + row) * D_ + n0 + r16] = sg + accR[mt][rr];
            }
    };

    const int bn0 = blockIdx.x;
    auto cb = [](int x) { return x < TOT ? x : TOT - 1; };

    // ---- prolog: fill the pipeline ----
    nidxLoad(bn0);
    gatherIssue(bn0);                 // kv,q for bn0 (one-time dependent stall)
    nidxLoad(cb(bn0 + stride));
    phaseW(wbuf[0]);                  // w(bn0)
    gatherIssue(cb(bn0 + stride));    // kv,q for bn0+s
    nidxLoad(cb(bn0 + 2 * stride));
    tload(bn0);                       // tf(bn0), both halves

    int buf = 0;
    for (int bn = bn0; bn < TOT; bn += stride) {
        const int nbuf = (buf == 2) ? 0 : buf + 1;
        phaseW(wbuf[nbuf]);           // w(bn+s) from prefetched kv/q (no mem stall)
        __syncthreads();              // drain-free: in-flight loads already consumed
        phaseM(bn, wbuf[buf]);        // tf(bn) prefetched; MFMA + epilogue
        gatherIssue(cb(bn + 2 * stride));  // post-barrier issue -> never drained
        nidxLoad(cb(bn + 3 * stride));
        tload(cb(bn + stride));       // t loads + cvt; tail also covers gather
        buf = nbuf;
    }
}

extern "C" void kernel_launch(void* const* d_in, const int* in_sizes, int n_in,
                              void* d_out, int out_size, void* d_ws, size_t ws_size,
                              hipStream_t stream) {
    const float* t_ij = (const float*)d_in[0];
    const float* x1   = (const float*)d_in[1];
    const float* x2   = (const float*)d_in[2];
    const int*   nidx = (const int*)  d_in[3];
    const float* Wq   = (const float*)d_in[4];
    const float* Wk1  = (const float*)d_in[5];
    const float* Wk2  = (const float*)d_in[6];
    const float* lnw  = (const float*)d_in[7];
    const float* eww  = (const float*)d_in[8];
    const float* rww  = (const float*)d_in[9];
    float* out = (float*)d_out;

    // ws layout: qws fp32 [bn][e][8] (16.78 MB) | kws bf16 [bn][e][8] (8.39 MB)
    float*  qws = (float*)d_ws;
    __bf16* kws = (__bf16*)(qws + (size_t)TOT * E_ * 8);

    proj_kernel<<<TOT / 4, 256, 0, stream>>>(x1, x2, Wq, Wk1, Wk2, qws, kws);
    fused_kernel<<<FGRID, 512, 0, stream>>>(t_ij, nidx, qws, kws, lnw, eww, rww, out);
}